// Round 9
// baseline (176.190 us; speedup 1.0000x reference)
//
#include <hip/hip_runtime.h>
#include <hip/hip_bf16.h>

#define NN 50000
#define EE 600000
#define FH 128
#define GG 128
#define CC 16
#define NBLK ((NN + 255) / 256)   // 196 scan blocks
#define GEMMB 782                 // 64-row gemm tiles
#define ZBLK ((8 * NN + 255) / 256)  // 1563 blocks to zero DEGC8

typedef __attribute__((ext_vector_type(8))) short bf16x8;
typedef __attribute__((ext_vector_type(4))) float f32x4;

#define FIXS 1.099511627776e12f   // 2^40
#define FIXI (1.0f / 1.099511627776e12f)

static __device__ __forceinline__ unsigned short f2bf(float f) {
    union { float f; unsigned int u; } v; v.f = f;
    unsigned int r = v.u + 0x7fffu + ((v.u >> 16) & 1u);   // RNE
    return (unsigned short)(r >> 16);
}
static __device__ __forceinline__ float bf2f(unsigned short h) {
    union { unsigned int u; float f; } v; v.u = ((unsigned int)h) << 16;
    return v.f;
}

// ---- prep: zero DEGC8 | transpose W1,W2 to bf16 | gstart binary search ----
__global__ __launch_bounds__(256) void k_prep(const float* __restrict__ W1,
                                              const float* __restrict__ W2,
                                              unsigned short* __restrict__ WT1,
                                              unsigned short* __restrict__ WT2,
                                              unsigned long long* __restrict__ degc8,
                                              const int* __restrict__ batch,
                                              int* __restrict__ gstart) {
    const int b = blockIdx.x, t = threadIdx.x;
    if (b < ZBLK) {
        int i = b * 256 + t;
        if (i < 8 * NN) degc8[i] = 0ULL;
    } else if (b < ZBLK + 128) {
        int o = (b - ZBLK) * 256 + t;          // 0..32767
        const float* W = (o < 16384) ? W1 : W2;
        unsigned short* WT = (o < 16384) ? WT1 : WT2;
        int oo = o & 16383;
        int c = oo >> 7, k = oo & 127;
        WT[oo] = f2bf(W[k * 128 + c]);
    } else {
        if (t <= GG) {
            int lo = 0, hi = NN;
            while (lo < hi) {
                int mid = (lo + hi) >> 1;
                if (batch[mid] < t) lo = mid + 1; else hi = mid;
            }
            gstart[t] = lo;
        }
    }
}

// ---- degree, 8-way privatized by blockIdx&7 (~XCD-local lines).
//      degc8[p][d] += {count:16 | ew*2^40:48}; rank[e] = (p<<16)|local_rank ----
__global__ __launch_bounds__(256) void k_deg(const int* __restrict__ dst,
                                             const float* __restrict__ ew,
                                             unsigned long long* __restrict__ degc8,
                                             int* __restrict__ rank) {
    int e = blockIdx.x * 256 + threadIdx.x;
    if (e < EE) {
        int d = dst[e];
        int p = blockIdx.x & 7;
        unsigned long long enc = (1ULL << 48) | (unsigned long long)(ew[e] * FIXS);
        unsigned long long old = atomicAdd(&degc8[(size_t)p * NN + d], enc);
        rank[e] = (int)((old >> 48) | ((unsigned)p << 16));
    }
}

// ---- scanA: fold 8 partitions -> dinv, per-partition bases, total count;
//      also per-block sums of counts for the scan ----
__global__ __launch_bounds__(256) void k_scanA(const unsigned long long* __restrict__ degc8,
                                               int* __restrict__ base8,
                                               int* __restrict__ cnt,
                                               int* __restrict__ bs,
                                               float* __restrict__ dinv) {
    int i = blockIdx.x * 256 + threadIdx.x;
    int run = 0;
    if (i < NN) {
        unsigned long long wsum = 0ULL;
#pragma unroll
        for (int p = 0; p < 8; p++) {
            unsigned long long d8 = degc8[(size_t)p * NN + i];
            base8[(size_t)p * NN + i] = run;
            run += (int)(d8 >> 48);
            wsum += (d8 & 0xFFFFFFFFFFFFULL);
        }
        float deg = (float)wsum * FIXI;
        dinv[i] = rsqrtf(deg + 1.0f);
        cnt[i] = run;
    }
    int v = run;
#pragma unroll
    for (int o = 32; o >= 1; o >>= 1) v += __shfl_down(v, o, 64);
    __shared__ int ws[4];
    if ((threadIdx.x & 63) == 0) ws[threadIdx.x >> 6] = v;
    __syncthreads();
    if (threadIdx.x == 0) bs[blockIdx.x] = ws[0] + ws[1] + ws[2] + ws[3];
}

// ---- scanBC: each block scans all block-sums in LDS (redundant, cheap),
//      takes its own exclusive offset, then scans its 256-count chunk ----
__global__ __launch_bounds__(256) void k_scanBC(const int* __restrict__ bs,
                                                const int* __restrict__ cnt,
                                                int* __restrict__ rowptr) {
    __shared__ int sb[256];
    __shared__ int sc[256];
    const int t = threadIdx.x, b = blockIdx.x;
    int vb = (t < NBLK) ? bs[t] : 0;
    sb[t] = vb;
    __syncthreads();
    for (int off = 1; off < 256; off <<= 1) {
        int add = (t >= off) ? sb[t - off] : 0;
        __syncthreads();
        sb[t] += add;
        __syncthreads();
    }
    const int boff = (b > 0) ? sb[b - 1] : 0;
    const int i = b * 256 + t;
    int v = (i < NN) ? cnt[i] : 0;
    sc[t] = v;
    __syncthreads();
    for (int off = 1; off < 256; off <<= 1) {
        int add = (t >= off) ? sc[t - off] : 0;
        __syncthreads();
        sc[t] += add;
        __syncthreads();
    }
    int excl = sc[t] - v + boff;
    if (i < NN) rowptr[i] = excl;
    if (i == 0) rowptr[NN] = EE;
}

// ---- fill CSR buckets, no atomics: pos = rowptr[d] + base8[p][d] + lr ----
__global__ __launch_bounds__(256) void k_binfill(const int* __restrict__ src,
                                                 const int* __restrict__ dst,
                                                 const float* __restrict__ ew,
                                                 const float* __restrict__ dinv,
                                                 const int* __restrict__ rowptr,
                                                 const int* __restrict__ base8,
                                                 const int* __restrict__ rank,
                                                 int2* __restrict__ bucket) {
    int e = blockIdx.x * 256 + threadIdx.x;
    if (e < EE) {
        int s = src[e], d = dst[e];
        int r = rank[e];
        int p = r >> 16, lr = r & 0xffff;
        float nm = dinv[s] * ew[e] * dinv[d];
        bucket[rowptr[d] + base8[(size_t)p * NN + d] + lr] = make_int2(s, __float_as_int(nm));
    }
}

// ---- MFMA GEMM: Y[bf16, nrows x 128] = Xin @ W (Wt pre-transposed bf16) ----
// 64-row tile / block, 4 waves, 32x64 each. 48KB LDS -> 3 blocks/CU.
template<int IN_F32>
__global__ __launch_bounds__(256, 3) void k_gemm_mfma(const void* __restrict__ Xin,
                                                      const unsigned short* __restrict__ Wt,
                                                      unsigned short* __restrict__ Y,
                                                      int nrows) {
    __shared__ char smem[49152];     // [0,32K)=Wl  [32K,48K)=Xl ; epilogue bounce aliases
    const int tid = threadIdx.x;
    const int r0 = blockIdx.x * 64;

    // stage: W = 2048 16B-chunks, X = 1024 chunks; 12 per thread
#pragma unroll
    for (int j = 0; j < 12; j++) {
        int ci = tid + 256 * j;
        if (ci < 2048) {             // W chunk
            int row = ci >> 4, slot = ci & 15;
            int loff = row * 256 + ((slot * 16) ^ ((row & 7) << 4));
            *(uint4*)(smem + loff) = ((const uint4*)Wt)[ci];
        } else {                     // X chunk
            int xci = ci - 2048;
            int row = xci >> 4, slot = xci & 15;
            int loff = 32768 + row * 256 + ((slot * 16) ^ ((row & 7) << 4));
            int grow = r0 + row;
            uint4 xv;
            if (IN_F32) {
                float4 f0 = make_float4(0.f, 0.f, 0.f, 0.f), f1 = f0;
                if (grow < nrows) {
                    const float4* xp = (const float4*)((const float*)Xin + (size_t)grow * 128 + slot * 8);
                    f0 = xp[0]; f1 = xp[1];
                }
                xv.x = (unsigned)f2bf(f0.x) | ((unsigned)f2bf(f0.y) << 16);
                xv.y = (unsigned)f2bf(f0.z) | ((unsigned)f2bf(f0.w) << 16);
                xv.z = (unsigned)f2bf(f1.x) | ((unsigned)f2bf(f1.y) << 16);
                xv.w = (unsigned)f2bf(f1.z) | ((unsigned)f2bf(f1.w) << 16);
            } else {
                xv = (grow < nrows)
                   ? ((const uint4*)((const unsigned short*)Xin + (size_t)grow * 128))[slot]
                   : make_uint4(0u, 0u, 0u, 0u);
            }
            *(uint4*)(smem + loff) = xv;
        }
    }
    __syncthreads();

    const int lane = tid & 63, w = tid >> 6;
    const int wr = (w >> 1) * 32, wc = (w & 1) * 64;   // 32 rows x 64 cols per wave
    const int lr = lane & 15, lg = lane >> 4;
    f32x4 acc[2][4];
#pragma unroll
    for (int a = 0; a < 2; a++)
#pragma unroll
        for (int c = 0; c < 4; c++) acc[a][c] = (f32x4){0.f, 0.f, 0.f, 0.f};

#pragma unroll
    for (int t = 0; t < 4; t++) {
        const int kb = t * 64 + lg * 16;
        bf16x8 af[2], bf[4];
#pragma unroll
        for (int i = 0; i < 2; i++) {
            int ar = wr + i * 16 + lr;
            af[i] = *(const bf16x8*)(smem + 32768 + ar * 256 + (kb ^ ((ar & 7) << 4)));
        }
#pragma unroll
        for (int i = 0; i < 4; i++) {
            int bc = wc + i * 16 + lr;
            bf[i] = *(const bf16x8*)(smem + bc * 256 + (kb ^ ((bc & 7) << 4)));
        }
#pragma unroll
        for (int fr = 0; fr < 2; fr++)
#pragma unroll
            for (int fc = 0; fc < 4; fc++)
                acc[fr][fc] = __builtin_amdgcn_mfma_f32_16x16x32_bf16(af[fr], bf[fc], acc[fr][fc], 0, 0, 0);
    }

    // epilogue: bounce through LDS (pitch 272B) for coalesced bf16 stores
    __syncthreads();
#pragma unroll
    for (int fr = 0; fr < 2; fr++)
#pragma unroll
        for (int fc = 0; fc < 4; fc++)
#pragma unroll
            for (int j = 0; j < 4; j++) {
                int row = wr + fr * 16 + lg * 4 + j;
                int col = wc + fc * 16 + lr;
                *(unsigned short*)(smem + row * 272 + col * 2) = f2bf(acc[fr][fc][j]);
            }
    __syncthreads();
#pragma unroll
    for (int j = 0; j < 4; j++) {
        int ci = tid + 256 * j;
        int row = ci >> 4, slot = ci & 15;
        int grow = r0 + row;
        if (grow < nrows)
            ((uint4*)(Y + (size_t)grow * 128))[slot] = *(const uint4*)(smem + row * 272 + slot * 16);
    }
}

// ---- gather-aggregate + self-loop + bias + relu (bf16 in/out) ----
// One wave per node; 4 edge-groups x 2-deep unroll = 8 row loads in flight.
__global__ __launch_bounds__(256) void k_gather(const unsigned short* __restrict__ XW,
                                                const int* __restrict__ rowptr,
                                                const int2* __restrict__ bucket,
                                                const float* __restrict__ dinv,
                                                const float* __restrict__ b,
                                                unsigned short* __restrict__ H) {
    const int wv = threadIdx.x >> 6, lane = threadIdx.x & 63;
    const int n = blockIdx.x * 4 + wv;
    if (n >= NN) return;
    const int eg = lane >> 4;        // edge group 0..3
    const int fl = lane & 15;        // 16B feature slot -> features 8*fl..8*fl+7
    const float di = dinv[n];
    const float sl = di * di;
    uint4 su = ((const uint4*)(XW + (size_t)n * 128))[fl];
    float acc[8];
#pragma unroll
    for (int q = 0; q < 8; q++) acc[q] = 0.f;
    const int e0 = rowptr[n], e1 = rowptr[n + 1];
    int e = e0 + eg;
    for (; e + 4 < e1; e += 8) {     // 2 edges per group per iter
        int2 p0 = bucket[e];
        int2 p1 = bucket[e + 4];
        float nm0 = __int_as_float(p0.y);
        float nm1 = __int_as_float(p1.y);
        uint4 v0 = ((const uint4*)(XW + (size_t)p0.x * 128))[fl];
        uint4 v1 = ((const uint4*)(XW + (size_t)p1.x * 128))[fl];
        unsigned int u0[4] = {v0.x, v0.y, v0.z, v0.w};
        unsigned int u1[4] = {v1.x, v1.y, v1.z, v1.w};
#pragma unroll
        for (int q = 0; q < 4; q++) {
            acc[2 * q]     = fmaf(__uint_as_float(u0[q] << 16), nm0, acc[2 * q]);
            acc[2 * q + 1] = fmaf(__uint_as_float(u0[q] & 0xffff0000u), nm0, acc[2 * q + 1]);
            acc[2 * q]     = fmaf(__uint_as_float(u1[q] << 16), nm1, acc[2 * q]);
            acc[2 * q + 1] = fmaf(__uint_as_float(u1[q] & 0xffff0000u), nm1, acc[2 * q + 1]);
        }
    }
    if (e < e1) {                    // tail edge for this group
        int2 p = bucket[e];
        float nm = __int_as_float(p.y);
        uint4 v = ((const uint4*)(XW + (size_t)p.x * 128))[fl];
        unsigned int uu[4] = {v.x, v.y, v.z, v.w};
#pragma unroll
        for (int q = 0; q < 4; q++) {
            acc[2 * q]     = fmaf(__uint_as_float(uu[q] << 16), nm, acc[2 * q]);
            acc[2 * q + 1] = fmaf(__uint_as_float(uu[q] & 0xffff0000u), nm, acc[2 * q + 1]);
        }
    }
#pragma unroll
    for (int q = 0; q < 8; q++) {
        acc[q] += __shfl_xor(acc[q], 16);
        acc[q] += __shfl_xor(acc[q], 32);
    }
    if (eg == 0) {
        unsigned int us[4] = {su.x, su.y, su.z, su.w};
        float4 b0 = ((const float4*)b)[fl * 2];
        float4 b1 = ((const float4*)b)[fl * 2 + 1];
        float bb[8] = {b0.x, b0.y, b0.z, b0.w, b1.x, b1.y, b1.z, b1.w};
        float r[8];
#pragma unroll
        for (int q = 0; q < 4; q++) {
            r[2 * q]     = fmaxf(fmaf(__uint_as_float(us[q] << 16), sl, acc[2 * q]) + bb[2 * q], 0.f);
            r[2 * q + 1] = fmaxf(fmaf(__uint_as_float(us[q] & 0xffff0000u), sl, acc[2 * q + 1]) + bb[2 * q + 1], 0.f);
        }
        uint4 o;
        o.x = (unsigned)f2bf(r[0]) | ((unsigned)f2bf(r[1]) << 16);
        o.y = (unsigned)f2bf(r[2]) | ((unsigned)f2bf(r[3]) << 16);
        o.z = (unsigned)f2bf(r[4]) | ((unsigned)f2bf(r[5]) << 16);
        o.w = (unsigned)f2bf(r[6]) | ((unsigned)f2bf(r[7]) << 16);
        ((uint4*)(H + (size_t)n * 128))[fl] = o;
    }
}

// ---- fused pooling + head: one block per graph, no atomics ----
__global__ __launch_bounds__(256) void k_poolhead(const unsigned short* __restrict__ H,
                                                  const int* __restrict__ gstart,
                                                  const float* __restrict__ linW,
                                                  const float* __restrict__ linb,
                                                  float* __restrict__ out) {
    __shared__ float lmx[512], lsm[512];
    __shared__ float mxf[128], mnf[128];
    const int g = blockIdx.x, t = threadIdx.x;
    const int slice = t >> 6;        // 0..3 node slices
    const int fp = t & 63;           // feature pair -> features 2fp, 2fp+1
    const int n0 = gstart[g], n1 = gstart[g + 1];
    float mx0 = 0.f, mx1 = 0.f, sm0 = 0.f, sm1 = 0.f;   // h >= 0 post-relu
    for (int n = n0 + slice; n < n1; n += 4) {
        unsigned int u = *(const unsigned int*)(H + (size_t)n * 128 + fp * 2);
        float v0 = bf2f((unsigned short)(u & 0xffffu));
        float v1 = bf2f((unsigned short)(u >> 16));
        mx0 = fmaxf(mx0, v0); mx1 = fmaxf(mx1, v1);
        sm0 += v0; sm1 += v1;
    }
    lmx[slice * 128 + fp * 2] = mx0; lmx[slice * 128 + fp * 2 + 1] = mx1;
    lsm[slice * 128 + fp * 2] = sm0; lsm[slice * 128 + fp * 2 + 1] = sm1;
    __syncthreads();
    if (t < 128) {
        float m = fmaxf(fmaxf(lmx[t], lmx[128 + t]), fmaxf(lmx[256 + t], lmx[384 + t]));
        float s = lsm[t] + lsm[128 + t] + lsm[256 + t] + lsm[384 + t];
        mxf[t] = m;
        mnf[t] = s / fmaxf((float)(n1 - n0), 1.0f);
    }
    __syncthreads();
    if (t < CC) {
        float z = linb[t];
        for (int f = 0; f < 128; f++) {
            z = fmaf(mxf[f], linW[f * CC + t], z);
            z = fmaf(mnf[f], linW[(128 + f) * CC + t], z);
        }
        float m = z;
        for (int o = 8; o >= 1; o >>= 1) m = fmaxf(m, __shfl_xor(m, o, 16));
        float ex = expf(z - m), s = ex;
        for (int o = 8; o >= 1; o >>= 1) s += __shfl_xor(s, o, 16);
        out[g * CC + t] = z - m - logf(s);
    }
}

extern "C" void kernel_launch(void* const* d_in, const int* in_sizes, int n_in,
                              void* d_out, int out_size, void* d_ws, size_t ws_size,
                              hipStream_t stream) {
    const float* x    = (const float*)d_in[0];
    const int*   ei   = (const int*)d_in[1];
    const float* ew   = (const float*)d_in[2];
    const int*   batch= (const int*)d_in[3];
    const float* W1   = (const float*)d_in[4];
    const float* b1   = (const float*)d_in[5];
    const float* W2   = (const float*)d_in[6];
    const float* b2   = (const float*)d_in[7];
    const float* linW = (const float*)d_in[8];
    const float* linb = (const float*)d_in[9];
    float* out = (float*)d_out;

    // workspace layout (8B-aligned blocks first)
    unsigned short* YB = (unsigned short*)d_ws;              // [N,128] bf16 gemm out
    unsigned short* HB = YB + (size_t)NN * 128;              // [N,128] bf16 gather out
    int2*  BUCKET = (int2*)(HB + (size_t)NN * 128);          // [E]
    unsigned long long* DEGC8 = (unsigned long long*)(BUCKET + EE);  // [8,N] packed
    int*   BASE8  = (int*)(DEGC8 + (size_t)8 * NN);          // [8,N]
    float* DINV   = (float*)(BASE8 + (size_t)8 * NN);        // [N]
    int*   CNT    = (int*)(DINV + NN);                       // [N]
    int*   ROWPTR = CNT + NN;                                // [N+1]
    int*   RANKE  = ROWPTR + NN + 1;                         // [E]
    int*   GSTART = RANKE + EE;                              // [G+1]
    int*   BS     = GSTART + GG + 1;                         // [NBLK]
    unsigned short* WT1 = (unsigned short*)(BS + NBLK);      // [128*128]
    unsigned short* WT2 = WT1 + 128 * 128;                   // [128*128]

    const int* src = ei;
    const int* dst = ei + EE;

    // prep: zero DEGC8 | W transpose | gstart
    k_prep<<<ZBLK + 128 + 1, 256, 0, stream>>>(W1, W2, WT1, WT2, DEGC8, batch, GSTART);

    // degree (privatized atomics) + layer-1 GEMM
    k_deg<<<(EE + 255) / 256, 256, 0, stream>>>(dst, ew, DEGC8, RANKE);
    k_gemm_mfma<1><<<GEMMB, 256, 0, stream>>>((const void*)x, WT1, YB, NN);

    // CSR build
    k_scanA<<<NBLK, 256, 0, stream>>>(DEGC8, BASE8, CNT, BS, DINV);
    k_scanBC<<<NBLK, 256, 0, stream>>>(BS, CNT, ROWPTR);
    k_binfill<<<(EE + 255) / 256, 256, 0, stream>>>(src, dst, ew, DINV, ROWPTR, BASE8, RANKE, BUCKET);

    // layer 1 aggregate
    k_gather<<<(NN + 3) / 4, 256, 0, stream>>>(YB, ROWPTR, BUCKET, DINV, b1, HB);

    // layer 2
    k_gemm_mfma<0><<<GEMMB, 256, 0, stream>>>((const void*)HB, WT2, YB, NN);
    k_gather<<<(NN + 3) / 4, 256, 0, stream>>>(YB, ROWPTR, BUCKET, DINV, b2, HB);

    // pooling + head (one block per graph)
    k_poolhead<<<GG, 256, 0, stream>>>(HB, GSTART, linW, linb, out);
}

// Round 10
// 160.805 us; speedup vs baseline: 1.0957x; 1.0957x over previous
//
#include <hip/hip_runtime.h>
#include <hip/hip_bf16.h>

#define NN 50000
#define EE 600000
#define FH 128
#define GG 128
#define CC 16
#define NBLK ((NN + 255) / 256)   // 196 scan blocks
#define GEMMB 782                 // 64-row gemm tiles
#define EPB 768                   // edges per gemm1 block (782*768 >= EE)

typedef __attribute__((ext_vector_type(8))) short bf16x8;
typedef __attribute__((ext_vector_type(4))) float f32x4;

#define FIXS 1.099511627776e12f   // 2^40
#define FIXI (1.0f / 1.099511627776e12f)

static __device__ __forceinline__ unsigned short f2bf(float f) {
    union { float f; unsigned int u; } v; v.f = f;
    unsigned int r = v.u + 0x7fffu + ((v.u >> 16) & 1u);   // RNE
    return (unsigned short)(r >> 16);
}
static __device__ __forceinline__ float bf2f(unsigned short h) {
    union { unsigned int u; float f; } v; v.u = ((unsigned int)h) << 16;
    return v.f;
}

// ---- prep: zero DEGC | transpose W1,W2 to bf16 | gstart binary search ----
__global__ __launch_bounds__(256) void k_prep(const float* __restrict__ W1,
                                              const float* __restrict__ W2,
                                              unsigned short* __restrict__ WT1,
                                              unsigned short* __restrict__ WT2,
                                              unsigned long long* __restrict__ degc,
                                              const int* __restrict__ batch,
                                              int* __restrict__ gstart) {
    const int b = blockIdx.x, t = threadIdx.x;
    if (b < NBLK) {
        int i = b * 256 + t;
        if (i < NN) degc[i] = 0ULL;
    } else if (b < NBLK + 128) {
        int o = (b - NBLK) * 256 + t;          // 0..32767
        const float* W = (o < 16384) ? W1 : W2;
        unsigned short* WT = (o < 16384) ? WT1 : WT2;
        int oo = o & 16383;
        int c = oo >> 7, k = oo & 127;
        WT[oo] = f2bf(W[k * 128 + c]);
    } else {
        if (t <= GG) {
            int lo = 0, hi = NN;
            while (lo < hi) {
                int mid = (lo + hi) >> 1;
                if (batch[mid] < t) lo = mid + 1; else hi = mid;
            }
            gstart[t] = lo;
        }
    }
}

// ---- MFMA GEMM, optionally with per-block deg tail-fused ----
// WITH_DEG=1: each block also owns EPB edges; one u64 atomic per edge packs
// {count:16 | ew*2^40:48}; returned old>>48 = edge's rank in its dst bin.
// Atomics issue after the MFMA loop; only the rank store waits on returns.
template<int IN_F32, int WITH_DEG>
__global__ __launch_bounds__(256, 3) void k_gemm_deg(const void* __restrict__ Xin,
                                                     const unsigned short* __restrict__ Wt,
                                                     unsigned short* __restrict__ Y,
                                                     int nrows,
                                                     const int* __restrict__ dst,
                                                     const float* __restrict__ ew,
                                                     unsigned long long* __restrict__ degc,
                                                     int* __restrict__ rank) {
    __shared__ char smem[49152];     // [0,32K)=Wl  [32K,48K)=Xl ; epilogue bounce aliases
    const int tid = threadIdx.x;
    const int r0 = blockIdx.x * 64;

    // stage: W = 2048 16B-chunks, X = 1024 chunks; 12 per thread
#pragma unroll
    for (int j = 0; j < 12; j++) {
        int ci = tid + 256 * j;
        if (ci < 2048) {             // W chunk
            int row = ci >> 4, slot = ci & 15;
            int loff = row * 256 + ((slot * 16) ^ ((row & 7) << 4));
            *(uint4*)(smem + loff) = ((const uint4*)Wt)[ci];
        } else {                     // X chunk
            int xci = ci - 2048;
            int row = xci >> 4, slot = xci & 15;
            int loff = 32768 + row * 256 + ((slot * 16) ^ ((row & 7) << 4));
            int grow = r0 + row;
            uint4 xv;
            if (IN_F32) {
                float4 f0 = make_float4(0.f, 0.f, 0.f, 0.f), f1 = f0;
                if (grow < nrows) {
                    const float4* xp = (const float4*)((const float*)Xin + (size_t)grow * 128 + slot * 8);
                    f0 = xp[0]; f1 = xp[1];
                }
                xv.x = (unsigned)f2bf(f0.x) | ((unsigned)f2bf(f0.y) << 16);
                xv.y = (unsigned)f2bf(f0.z) | ((unsigned)f2bf(f0.w) << 16);
                xv.z = (unsigned)f2bf(f1.x) | ((unsigned)f2bf(f1.y) << 16);
                xv.w = (unsigned)f2bf(f1.z) | ((unsigned)f2bf(f1.w) << 16);
            } else {
                xv = (grow < nrows)
                   ? ((const uint4*)((const unsigned short*)Xin + (size_t)grow * 128))[slot]
                   : make_uint4(0u, 0u, 0u, 0u);
            }
            *(uint4*)(smem + loff) = xv;
        }
    }

    // issue this block's edge loads (latency drains under the MFMA loop)
    int   ed[3];
    float ev[3];
    if (WITH_DEG) {
#pragma unroll
        for (int j = 0; j < 3; j++) {
            int e = blockIdx.x * EPB + tid + 256 * j;
            if (e < EE) { ed[j] = dst[e]; ev[j] = ew[e]; }
            else        { ed[j] = -1;     ev[j] = 0.f;  }
        }
    }
    __syncthreads();

    const int lane = tid & 63, w = tid >> 6;
    const int wr = (w >> 1) * 32, wc = (w & 1) * 64;   // 32 rows x 64 cols per wave
    const int lr = lane & 15, lg = lane >> 4;
    f32x4 acc[2][4];
#pragma unroll
    for (int a = 0; a < 2; a++)
#pragma unroll
        for (int c = 0; c < 4; c++) acc[a][c] = (f32x4){0.f, 0.f, 0.f, 0.f};

#pragma unroll
    for (int t = 0; t < 4; t++) {
        const int kb = t * 64 + lg * 16;
        bf16x8 af[2], bf[4];
#pragma unroll
        for (int i = 0; i < 2; i++) {
            int ar = wr + i * 16 + lr;
            af[i] = *(const bf16x8*)(smem + 32768 + ar * 256 + (kb ^ ((ar & 7) << 4)));
        }
#pragma unroll
        for (int i = 0; i < 4; i++) {
            int bc = wc + i * 16 + lr;
            bf[i] = *(const bf16x8*)(smem + bc * 256 + (kb ^ ((bc & 7) << 4)));
        }
#pragma unroll
        for (int fr = 0; fr < 2; fr++)
#pragma unroll
            for (int fc = 0; fc < 4; fc++)
                acc[fr][fc] = __builtin_amdgcn_mfma_f32_16x16x32_bf16(af[fr], bf[fc], acc[fr][fc], 0, 0, 0);
    }

    // fire the degree atomics now; wait for returns only at the rank store
    unsigned long long old0 = 0ULL, old1 = 0ULL, old2 = 0ULL;
    if (WITH_DEG) {
        if (ed[0] >= 0) old0 = atomicAdd(&degc[ed[0]], (1ULL << 48) | (unsigned long long)(ev[0] * FIXS));
        if (ed[1] >= 0) old1 = atomicAdd(&degc[ed[1]], (1ULL << 48) | (unsigned long long)(ev[1] * FIXS));
        if (ed[2] >= 0) old2 = atomicAdd(&degc[ed[2]], (1ULL << 48) | (unsigned long long)(ev[2] * FIXS));
    }

    // epilogue: bounce through LDS (pitch 272B) for coalesced bf16 stores
    __syncthreads();
#pragma unroll
    for (int fr = 0; fr < 2; fr++)
#pragma unroll
        for (int fc = 0; fc < 4; fc++)
#pragma unroll
            for (int j = 0; j < 4; j++) {
                int row = wr + fr * 16 + lg * 4 + j;
                int col = wc + fc * 16 + lr;
                *(unsigned short*)(smem + row * 272 + col * 2) = f2bf(acc[fr][fc][j]);
            }
    __syncthreads();
#pragma unroll
    for (int j = 0; j < 4; j++) {
        int ci = tid + 256 * j;
        int row = ci >> 4, slot = ci & 15;
        int grow = r0 + row;
        if (grow < nrows)
            ((uint4*)(Y + (size_t)grow * 128))[slot] = *(const uint4*)(smem + row * 272 + slot * 16);
    }

    if (WITH_DEG) {
        int e0 = blockIdx.x * EPB + tid;
        if (ed[0] >= 0) rank[e0]       = (int)(old0 >> 48);
        if (ed[1] >= 0) rank[e0 + 256] = (int)(old1 >> 48);
        if (ed[2] >= 0) rank[e0 + 512] = (int)(old2 >> 48);
    }
}

// ---- scanA: per-block sums of counts; also dinv = rsqrt(deg+1) ----
__global__ __launch_bounds__(256) void k_scanA(const unsigned long long* __restrict__ degc,
                                               int* __restrict__ bs,
                                               float* __restrict__ dinv) {
    int i = blockIdx.x * 256 + threadIdx.x;
    int v = 0;
    if (i < NN) {
        unsigned long long d = degc[i];
        v = (int)(d >> 48);
        float deg = (float)(d & 0xFFFFFFFFFFFFULL) * FIXI;
        dinv[i] = rsqrtf(deg + 1.0f);
    }
#pragma unroll
    for (int o = 32; o >= 1; o >>= 1) v += __shfl_down(v, o, 64);
    __shared__ int ws[4];
    if ((threadIdx.x & 63) == 0) ws[threadIdx.x >> 6] = v;
    __syncthreads();
    if (threadIdx.x == 0) bs[blockIdx.x] = ws[0] + ws[1] + ws[2] + ws[3];
}

// ---- scanBC: each block scans all block-sums in LDS (redundant, cheap),
//      takes its own exclusive offset, then scans its 256-count chunk ----
__global__ __launch_bounds__(256) void k_scanBC(const int* __restrict__ bs,
                                                const unsigned long long* __restrict__ degc,
                                                int* __restrict__ rowptr) {
    __shared__ int sb[256];
    __shared__ int sc[256];
    const int t = threadIdx.x, b = blockIdx.x;
    int vb = (t < NBLK) ? bs[t] : 0;
    sb[t] = vb;
    __syncthreads();
    for (int off = 1; off < 256; off <<= 1) {
        int add = (t >= off) ? sb[t - off] : 0;
        __syncthreads();
        sb[t] += add;
        __syncthreads();
    }
    const int boff = (b > 0) ? sb[b - 1] : 0;
    const int i = b * 256 + t;
    int v = (i < NN) ? (int)(degc[i] >> 48) : 0;
    sc[t] = v;
    __syncthreads();
    for (int off = 1; off < 256; off <<= 1) {
        int add = (t >= off) ? sc[t - off] : 0;
        __syncthreads();
        sc[t] += add;
        __syncthreads();
    }
    int excl = sc[t] - v + boff;
    if (i < NN) rowptr[i] = excl;
    if (i == 0) rowptr[NN] = EE;
}

// ---- fill CSR buckets, no atomics: pos = rowptr[d] + rank[e] ----
__global__ __launch_bounds__(256) void k_binfill(const int* __restrict__ src,
                                                 const int* __restrict__ dst,
                                                 const float* __restrict__ ew,
                                                 const float* __restrict__ dinv,
                                                 const int* __restrict__ rowptr,
                                                 const int* __restrict__ rank,
                                                 int2* __restrict__ bucket) {
    int e = blockIdx.x * 256 + threadIdx.x;
    if (e < EE) {
        int s = src[e], d = dst[e];
        float nm = dinv[s] * ew[e] * dinv[d];
        bucket[rowptr[d] + rank[e]] = make_int2(s, __float_as_int(nm));
    }
}

// ---- gather-aggregate + self-loop + bias + relu (bf16 in/out) ----
// One wave per node; 4 edge-groups x 2-deep unroll = 8 row loads in flight.
__global__ __launch_bounds__(256) void k_gather(const unsigned short* __restrict__ XW,
                                                const int* __restrict__ rowptr,
                                                const int2* __restrict__ bucket,
                                                const float* __restrict__ dinv,
                                                const float* __restrict__ b,
                                                unsigned short* __restrict__ H) {
    const int wv = threadIdx.x >> 6, lane = threadIdx.x & 63;
    const int n = blockIdx.x * 4 + wv;
    if (n >= NN) return;
    const int eg = lane >> 4;        // edge group 0..3
    const int fl = lane & 15;        // 16B feature slot -> features 8*fl..8*fl+7
    const float di = dinv[n];
    const float sl = di * di;
    uint4 su = ((const uint4*)(XW + (size_t)n * 128))[fl];
    float acc[8];
#pragma unroll
    for (int q = 0; q < 8; q++) acc[q] = 0.f;
    const int e0 = rowptr[n], e1 = rowptr[n + 1];
    int e = e0 + eg;
    for (; e + 4 < e1; e += 8) {     // 2 edges per group per iter
        int2 p0 = bucket[e];
        int2 p1 = bucket[e + 4];
        float nm0 = __int_as_float(p0.y);
        float nm1 = __int_as_float(p1.y);
        uint4 v0 = ((const uint4*)(XW + (size_t)p0.x * 128))[fl];
        uint4 v1 = ((const uint4*)(XW + (size_t)p1.x * 128))[fl];
        unsigned int u0[4] = {v0.x, v0.y, v0.z, v0.w};
        unsigned int u1[4] = {v1.x, v1.y, v1.z, v1.w};
#pragma unroll
        for (int q = 0; q < 4; q++) {
            acc[2 * q]     = fmaf(__uint_as_float(u0[q] << 16), nm0, acc[2 * q]);
            acc[2 * q + 1] = fmaf(__uint_as_float(u0[q] & 0xffff0000u), nm0, acc[2 * q + 1]);
            acc[2 * q]     = fmaf(__uint_as_float(u1[q] << 16), nm1, acc[2 * q]);
            acc[2 * q + 1] = fmaf(__uint_as_float(u1[q] & 0xffff0000u), nm1, acc[2 * q + 1]);
        }
    }
    if (e < e1) {                    // tail edge for this group
        int2 p = bucket[e];
        float nm = __int_as_float(p.y);
        uint4 v = ((const uint4*)(XW + (size_t)p.x * 128))[fl];
        unsigned int uu[4] = {v.x, v.y, v.z, v.w};
#pragma unroll
        for (int q = 0; q < 4; q++) {
            acc[2 * q]     = fmaf(__uint_as_float(uu[q] << 16), nm, acc[2 * q]);
            acc[2 * q + 1] = fmaf(__uint_as_float(uu[q] & 0xffff0000u), nm, acc[2 * q + 1]);
        }
    }
#pragma unroll
    for (int q = 0; q < 8; q++) {
        acc[q] += __shfl_xor(acc[q], 16);
        acc[q] += __shfl_xor(acc[q], 32);
    }
    if (eg == 0) {
        unsigned int us[4] = {su.x, su.y, su.z, su.w};
        float4 b0 = ((const float4*)b)[fl * 2];
        float4 b1 = ((const float4*)b)[fl * 2 + 1];
        float bb[8] = {b0.x, b0.y, b0.z, b0.w, b1.x, b1.y, b1.z, b1.w};
        float r[8];
#pragma unroll
        for (int q = 0; q < 4; q++) {
            r[2 * q]     = fmaxf(fmaf(__uint_as_float(us[q] << 16), sl, acc[2 * q]) + bb[2 * q], 0.f);
            r[2 * q + 1] = fmaxf(fmaf(__uint_as_float(us[q] & 0xffff0000u), sl, acc[2 * q + 1]) + bb[2 * q + 1], 0.f);
        }
        uint4 o;
        o.x = (unsigned)f2bf(r[0]) | ((unsigned)f2bf(r[1]) << 16);
        o.y = (unsigned)f2bf(r[2]) | ((unsigned)f2bf(r[3]) << 16);
        o.z = (unsigned)f2bf(r[4]) | ((unsigned)f2bf(r[5]) << 16);
        o.w = (unsigned)f2bf(r[6]) | ((unsigned)f2bf(r[7]) << 16);
        ((uint4*)(H + (size_t)n * 128))[fl] = o;
    }
}

// ---- fused pooling + head: one 512-thread block per graph, no atomics ----
__global__ __launch_bounds__(512) void k_poolhead(const unsigned short* __restrict__ H,
                                                  const int* __restrict__ gstart,
                                                  const float* __restrict__ linW,
                                                  const float* __restrict__ linb,
                                                  float* __restrict__ out) {
    __shared__ float lmx[1024], lsm[1024];
    __shared__ float mxf[128], mnf[128];
    const int g = blockIdx.x, t = threadIdx.x;
    const int slice = t >> 6;        // 0..7 node slices
    const int fp = t & 63;           // feature pair -> features 2fp, 2fp+1
    const int n0 = gstart[g], n1 = gstart[g + 1];
    float mx0 = 0.f, mx1 = 0.f, sm0 = 0.f, sm1 = 0.f;   // h >= 0 post-relu
    for (int n = n0 + slice; n < n1; n += 8) {
        unsigned int u = *(const unsigned int*)(H + (size_t)n * 128 + fp * 2);
        float v0 = bf2f((unsigned short)(u & 0xffffu));
        float v1 = bf2f((unsigned short)(u >> 16));
        mx0 = fmaxf(mx0, v0); mx1 = fmaxf(mx1, v1);
        sm0 += v0; sm1 += v1;
    }
    lmx[slice * 128 + fp * 2] = mx0; lmx[slice * 128 + fp * 2 + 1] = mx1;
    lsm[slice * 128 + fp * 2] = sm0; lsm[slice * 128 + fp * 2 + 1] = sm1;
    __syncthreads();
    if (t < 128) {
        float m = 0.f, s = 0.f;
#pragma unroll
        for (int q = 0; q < 8; q++) {
            m = fmaxf(m, lmx[q * 128 + t]);
            s += lsm[q * 128 + t];
        }
        mxf[t] = m;
        mnf[t] = s / fmaxf((float)(n1 - n0), 1.0f);
    }
    __syncthreads();
    if (t < CC) {
        float z = linb[t];
        for (int f = 0; f < 128; f++) {
            z = fmaf(mxf[f], linW[f * CC + t], z);
            z = fmaf(mnf[f], linW[(128 + f) * CC + t], z);
        }
        float m = z;
        for (int o = 8; o >= 1; o >>= 1) m = fmaxf(m, __shfl_xor(m, o, 16));
        float ex = expf(z - m), s = ex;
        for (int o = 8; o >= 1; o >>= 1) s += __shfl_xor(s, o, 16);
        out[g * CC + t] = z - m - logf(s);
    }
}

extern "C" void kernel_launch(void* const* d_in, const int* in_sizes, int n_in,
                              void* d_out, int out_size, void* d_ws, size_t ws_size,
                              hipStream_t stream) {
    const float* x    = (const float*)d_in[0];
    const int*   ei   = (const int*)d_in[1];
    const float* ew   = (const float*)d_in[2];
    const int*   batch= (const int*)d_in[3];
    const float* W1   = (const float*)d_in[4];
    const float* b1   = (const float*)d_in[5];
    const float* W2   = (const float*)d_in[6];
    const float* b2   = (const float*)d_in[7];
    const float* linW = (const float*)d_in[8];
    const float* linb = (const float*)d_in[9];
    float* out = (float*)d_out;

    // workspace layout (8B-aligned blocks first)
    unsigned short* YB = (unsigned short*)d_ws;              // [N,128] bf16 gemm out
    unsigned short* HB = YB + (size_t)NN * 128;              // [N,128] bf16 gather out
    int2*  BUCKET = (int2*)(HB + (size_t)NN * 128);          // [E]
    unsigned long long* DEGC = (unsigned long long*)(BUCKET + EE);  // [N] packed
    float* DINV   = (float*)(DEGC + NN);                     // [N]
    int*   ROWPTR = (int*)(DINV + NN);                       // [N+1]
    int*   RANKE  = ROWPTR + NN + 1;                         // [E]
    int*   GSTART = RANKE + EE;                              // [G+1]
    int*   BS     = GSTART + GG + 1;                         // [NBLK]
    unsigned short* WT1 = (unsigned short*)(BS + NBLK);      // [128*128]
    unsigned short* WT2 = WT1 + 128 * 128;                   // [128*128]

    const int* src = ei;
    const int* dst = ei + EE;

    // prep: zero DEGC | W transpose | gstart
    k_prep<<<NBLK + 128 + 1, 256, 0, stream>>>(W1, W2, WT1, WT2, DEGC, batch, GSTART);

    // layer-1 GEMM with deg tail-fused into every block
    k_gemm_deg<1, 1><<<GEMMB, 256, 0, stream>>>((const void*)x, WT1, YB, NN,
                                                dst, ew, DEGC, RANKE);

    // CSR build
    k_scanA<<<NBLK, 256, 0, stream>>>(DEGC, BS, DINV);
    k_scanBC<<<NBLK, 256, 0, stream>>>(BS, DEGC, ROWPTR);
    k_binfill<<<(EE + 255) / 256, 256, 0, stream>>>(src, dst, ew, DINV, ROWPTR, RANKE, BUCKET);

    // layer 1 aggregate
    k_gather<<<(NN + 3) / 4, 256, 0, stream>>>(YB, ROWPTR, BUCKET, DINV, b1, HB);

    // layer 2
    k_gemm_deg<0, 0><<<GEMMB, 256, 0, stream>>>((const void*)HB, WT2, YB, NN,
                                                nullptr, nullptr, nullptr, nullptr);
    k_gather<<<(NN + 3) / 4, 256, 0, stream>>>(YB, ROWPTR, BUCKET, DINV, b2, HB);

    // pooling + head (one block per graph)
    k_poolhead<<<GG, 512, 0, stream>>>(HB, GSTART, linW, linb, out);
}

// Round 11
// 156.869 us; speedup vs baseline: 1.1232x; 1.0251x over previous
//
#include <hip/hip_runtime.h>
#include <hip/hip_bf16.h>

#define NN 50000
#define EE 600000
#define FH 128
#define GG 128
#define CC 16
#define NBLK ((NN + 255) / 256)   // 196 scan blocks
#define GEMMB 782                 // 64-row gemm tiles
#define EPB 768                   // edges per gemm1 block (782*768 >= EE)
#define CONVB 3125                // x->bf16 conversion blocks (800000 threads, 8 elem/thread)

typedef __attribute__((ext_vector_type(8))) short bf16x8;
typedef __attribute__((ext_vector_type(4))) float f32x4;

#define FIXS 1.099511627776e12f   // 2^40
#define FIXI (1.0f / 1.099511627776e12f)

static __device__ __forceinline__ unsigned short f2bf(float f) {
    union { float f; unsigned int u; } v; v.f = f;
    unsigned int r = v.u + 0x7fffu + ((v.u >> 16) & 1u);   // RNE
    return (unsigned short)(r >> 16);
}
static __device__ __forceinline__ float bf2f(unsigned short h) {
    union { unsigned int u; float f; } v; v.u = ((unsigned int)h) << 16;
    return v.f;
}
// async global->LDS, 16B per lane; lds base must be wave-uniform
static __device__ __forceinline__ void ld16(const void* g, void* l) {
    __builtin_amdgcn_global_load_lds((const __attribute__((address_space(1))) void*)g,
                                     (__attribute__((address_space(3))) void*)l, 16, 0, 0);
}

// ---- prep: x->bf16 XB | zero DEGC | transpose W1,W2 to bf16 | gstart ----
__global__ __launch_bounds__(256) void k_prep(const float* __restrict__ x,
                                              unsigned short* __restrict__ XB,
                                              const float* __restrict__ W1,
                                              const float* __restrict__ W2,
                                              unsigned short* __restrict__ WT1,
                                              unsigned short* __restrict__ WT2,
                                              unsigned long long* __restrict__ degc,
                                              const int* __restrict__ batch,
                                              int* __restrict__ gstart) {
    const int b = blockIdx.x, t = threadIdx.x;
    if (b < NBLK) {
        int i = b * 256 + t;
        if (i < NN) degc[i] = 0ULL;
    } else if (b < NBLK + 128) {
        int o = (b - NBLK) * 256 + t;          // 0..32767
        const float* W = (o < 16384) ? W1 : W2;
        unsigned short* WT = (o < 16384) ? WT1 : WT2;
        int oo = o & 16383;
        int c = oo >> 7, k = oo & 127;
        WT[oo] = f2bf(W[k * 128 + c]);
    } else if (b < NBLK + 129) {
        if (t <= GG) {
            int lo = 0, hi = NN;
            while (lo < hi) {
                int mid = (lo + hi) >> 1;
                if (batch[mid] < t) lo = mid + 1; else hi = mid;
            }
            gstart[t] = lo;
        }
    } else {
        int o = (b - NBLK - 129) * 256 + t;    // 0..799999, 8 floats each
        const float4* xp = (const float4*)x + (size_t)o * 2;
        float4 f0 = xp[0], f1 = xp[1];
        uint4 v;
        v.x = (unsigned)f2bf(f0.x) | ((unsigned)f2bf(f0.y) << 16);
        v.y = (unsigned)f2bf(f0.z) | ((unsigned)f2bf(f0.w) << 16);
        v.z = (unsigned)f2bf(f1.x) | ((unsigned)f2bf(f1.y) << 16);
        v.w = (unsigned)f2bf(f1.z) | ((unsigned)f2bf(f1.w) << 16);
        ((uint4*)XB)[o] = v;
    }
}

// ---- MFMA GEMM (bf16 in, bf16 out), async global_load_lds staging ----
// LDS linear [W: 0..32K | X: 32K..48K]; source column pre-swizzled slot^=(row&7)
// so the reader's byte-XOR (row&7)<<4 lands on the right data (rule #21).
// WITH_DEG=1: per-block EPB edges; u64 atomic packs {count:16|ew*2^40:48};
// old>>48 = edge's rank in its dst bin. Atomics fire after the MFMA loop.
template<int WITH_DEG>
__global__ __launch_bounds__(256, 3) void k_gemm_deg(const unsigned short* __restrict__ Xin,
                                                     const unsigned short* __restrict__ Wt,
                                                     unsigned short* __restrict__ Y,
                                                     int nrows,
                                                     const int* __restrict__ dst,
                                                     const float* __restrict__ ew,
                                                     unsigned long long* __restrict__ degc,
                                                     int* __restrict__ rank) {
    __shared__ char smem[49152];
    const int tid = threadIdx.x;
    const int lane = tid & 63, w = tid >> 6;
    const int r0 = blockIdx.x * 64;
    const char* Wb = (const char*)Wt;
    const char* Xb = (const char*)Xin;

    // stage: 48 wave-iterations of 1KB each (12 per wave), all async in flight
#pragma unroll
    for (int j = 0; j < 12; j++) {
        const int base = (j * 4 + w) * 64;     // chunk index of lane 0 (uniform)
        const int ci = base + lane;            // 0..3071
        char* ldst = smem + (size_t)base * 16; // linear LDS dest
        if (base < 2048) {                     // W chunks (uniform branch)
            int row = ci >> 4, slot = ci & 15;
            ld16(Wb + row * 256 + ((slot ^ (row & 7)) * 16), ldst);
        } else {                               // X chunks
            int xci = ci - 2048;
            int row = xci >> 4, slot = xci & 15;
            ld16(Xb + (size_t)(r0 + row) * 256 + ((slot ^ (row & 7)) * 16), ldst);
        }
    }

    // this block's edge loads (drain under the same waitcnt as staging)
    int   ed[3];
    float ev[3];
    if (WITH_DEG) {
#pragma unroll
        for (int j = 0; j < 3; j++) {
            int e = blockIdx.x * EPB + tid + 256 * j;
            if (e < EE) { ed[j] = dst[e]; ev[j] = ew[e]; }
            else        { ed[j] = -1;     ev[j] = 0.f;  }
        }
    }
    __syncthreads();

    const int wr = (w >> 1) * 32, wc = (w & 1) * 64;   // 32 rows x 64 cols per wave
    const int lr = lane & 15, lg = lane >> 4;
    f32x4 acc[2][4];
#pragma unroll
    for (int a = 0; a < 2; a++)
#pragma unroll
        for (int c = 0; c < 4; c++) acc[a][c] = (f32x4){0.f, 0.f, 0.f, 0.f};

#pragma unroll
    for (int t = 0; t < 4; t++) {
        const int kb = t * 64 + lg * 16;
        bf16x8 af[2], bf[4];
#pragma unroll
        for (int i = 0; i < 2; i++) {
            int ar = wr + i * 16 + lr;
            af[i] = *(const bf16x8*)(smem + 32768 + ar * 256 + (kb ^ ((ar & 7) << 4)));
        }
#pragma unroll
        for (int i = 0; i < 4; i++) {
            int bc = wc + i * 16 + lr;
            bf[i] = *(const bf16x8*)(smem + bc * 256 + (kb ^ ((bc & 7) << 4)));
        }
#pragma unroll
        for (int fr = 0; fr < 2; fr++)
#pragma unroll
            for (int fc = 0; fc < 4; fc++)
                acc[fr][fc] = __builtin_amdgcn_mfma_f32_16x16x32_bf16(af[fr], bf[fc], acc[fr][fc], 0, 0, 0);
    }

    // fire the degree atomics now; wait for returns only at the rank store
    unsigned long long old0 = 0ULL, old1 = 0ULL, old2 = 0ULL;
    if (WITH_DEG) {
        if (ed[0] >= 0) old0 = atomicAdd(&degc[ed[0]], (1ULL << 48) | (unsigned long long)(ev[0] * FIXS));
        if (ed[1] >= 0) old1 = atomicAdd(&degc[ed[1]], (1ULL << 48) | (unsigned long long)(ev[1] * FIXS));
        if (ed[2] >= 0) old2 = atomicAdd(&degc[ed[2]], (1ULL << 48) | (unsigned long long)(ev[2] * FIXS));
    }

    // epilogue: bounce through LDS (pitch 272B) for coalesced bf16 stores
    __syncthreads();
#pragma unroll
    for (int fr = 0; fr < 2; fr++)
#pragma unroll
        for (int fc = 0; fc < 4; fc++)
#pragma unroll
            for (int j = 0; j < 4; j++) {
                int row = wr + fr * 16 + lg * 4 + j;
                int col = wc + fc * 16 + lr;
                *(unsigned short*)(smem + row * 272 + col * 2) = f2bf(acc[fr][fc][j]);
            }
    __syncthreads();
#pragma unroll
    for (int j = 0; j < 4; j++) {
        int ci = tid + 256 * j;
        int row = ci >> 4, slot = ci & 15;
        int grow = r0 + row;
        if (grow < nrows)
            ((uint4*)(Y + (size_t)grow * 128))[slot] = *(const uint4*)(smem + row * 272 + slot * 16);
    }

    if (WITH_DEG) {
        int e0 = blockIdx.x * EPB + tid;
        if (ed[0] >= 0) rank[e0]       = (int)(old0 >> 48);
        if (ed[1] >= 0) rank[e0 + 256] = (int)(old1 >> 48);
        if (ed[2] >= 0) rank[e0 + 512] = (int)(old2 >> 48);
    }
}

// ---- scanA: per-block sums of counts; also dinv = rsqrt(deg+1) ----
__global__ __launch_bounds__(256) void k_scanA(const unsigned long long* __restrict__ degc,
                                               int* __restrict__ bs,
                                               float* __restrict__ dinv) {
    int i = blockIdx.x * 256 + threadIdx.x;
    int v = 0;
    if (i < NN) {
        unsigned long long d = degc[i];
        v = (int)(d >> 48);
        float deg = (float)(d & 0xFFFFFFFFFFFFULL) * FIXI;
        dinv[i] = rsqrtf(deg + 1.0f);
    }
#pragma unroll
    for (int o = 32; o >= 1; o >>= 1) v += __shfl_down(v, o, 64);
    __shared__ int ws[4];
    if ((threadIdx.x & 63) == 0) ws[threadIdx.x >> 6] = v;
    __syncthreads();
    if (threadIdx.x == 0) bs[blockIdx.x] = ws[0] + ws[1] + ws[2] + ws[3];
}

// ---- scanBC: redundant block-sum scan in LDS + per-chunk scan -> rowptr ----
__global__ __launch_bounds__(256) void k_scanBC(const int* __restrict__ bs,
                                                const unsigned long long* __restrict__ degc,
                                                int* __restrict__ rowptr) {
    __shared__ int sb[256];
    __shared__ int sc[256];
    const int t = threadIdx.x, b = blockIdx.x;
    int vb = (t < NBLK) ? bs[t] : 0;
    sb[t] = vb;
    __syncthreads();
    for (int off = 1; off < 256; off <<= 1) {
        int add = (t >= off) ? sb[t - off] : 0;
        __syncthreads();
        sb[t] += add;
        __syncthreads();
    }
    const int boff = (b > 0) ? sb[b - 1] : 0;
    const int i = b * 256 + t;
    int v = (i < NN) ? (int)(degc[i] >> 48) : 0;
    sc[t] = v;
    __syncthreads();
    for (int off = 1; off < 256; off <<= 1) {
        int add = (t >= off) ? sc[t - off] : 0;
        __syncthreads();
        sc[t] += add;
        __syncthreads();
    }
    int excl = sc[t] - v + boff;
    if (i < NN) rowptr[i] = excl;
    if (i == 0) rowptr[NN] = EE;
}

// ---- fill CSR buckets, no atomics: pos = rowptr[d] + rank[e] ----
__global__ __launch_bounds__(256) void k_binfill(const int* __restrict__ src,
                                                 const int* __restrict__ dst,
                                                 const float* __restrict__ ew,
                                                 const float* __restrict__ dinv,
                                                 const int* __restrict__ rowptr,
                                                 const int* __restrict__ rank,
                                                 int2* __restrict__ bucket) {
    int e = blockIdx.x * 256 + threadIdx.x;
    if (e < EE) {
        int s = src[e], d = dst[e];
        float nm = dinv[s] * ew[e] * dinv[d];
        bucket[rowptr[d] + rank[e]] = make_int2(s, __float_as_int(nm));
    }
}

// ---- gather-aggregate + self-loop + bias + relu (bf16 in/out) ----
__global__ __launch_bounds__(256) void k_gather(const unsigned short* __restrict__ XW,
                                                const int* __restrict__ rowptr,
                                                const int2* __restrict__ bucket,
                                                const float* __restrict__ dinv,
                                                const float* __restrict__ b,
                                                unsigned short* __restrict__ H) {
    const int wv = threadIdx.x >> 6, lane = threadIdx.x & 63;
    const int n = blockIdx.x * 4 + wv;
    if (n >= NN) return;
    const int eg = lane >> 4;        // edge group 0..3
    const int fl = lane & 15;        // 16B feature slot
    const float di = dinv[n];
    const float sl = di * di;
    uint4 su = ((const uint4*)(XW + (size_t)n * 128))[fl];
    float acc[8];
#pragma unroll
    for (int q = 0; q < 8; q++) acc[q] = 0.f;
    const int e0 = rowptr[n], e1 = rowptr[n + 1];
    int e = e0 + eg;
    for (; e + 4 < e1; e += 8) {
        int2 p0 = bucket[e];
        int2 p1 = bucket[e + 4];
        float nm0 = __int_as_float(p0.y);
        float nm1 = __int_as_float(p1.y);
        uint4 v0 = ((const uint4*)(XW + (size_t)p0.x * 128))[fl];
        uint4 v1 = ((const uint4*)(XW + (size_t)p1.x * 128))[fl];
        unsigned int u0[4] = {v0.x, v0.y, v0.z, v0.w};
        unsigned int u1[4] = {v1.x, v1.y, v1.z, v1.w};
#pragma unroll
        for (int q = 0; q < 4; q++) {
            acc[2 * q]     = fmaf(__uint_as_float(u0[q] << 16), nm0, acc[2 * q]);
            acc[2 * q + 1] = fmaf(__uint_as_float(u0[q] & 0xffff0000u), nm0, acc[2 * q + 1]);
            acc[2 * q]     = fmaf(__uint_as_float(u1[q] << 16), nm1, acc[2 * q]);
            acc[2 * q + 1] = fmaf(__uint_as_float(u1[q] & 0xffff0000u), nm1, acc[2 * q + 1]);
        }
    }
    if (e < e1) {
        int2 p = bucket[e];
        float nm = __int_as_float(p.y);
        uint4 v = ((const uint4*)(XW + (size_t)p.x * 128))[fl];
        unsigned int uu[4] = {v.x, v.y, v.z, v.w};
#pragma unroll
        for (int q = 0; q < 4; q++) {
            acc[2 * q]     = fmaf(__uint_as_float(uu[q] << 16), nm, acc[2 * q]);
            acc[2 * q + 1] = fmaf(__uint_as_float(uu[q] & 0xffff0000u), nm, acc[2 * q + 1]);
        }
    }
#pragma unroll
    for (int q = 0; q < 8; q++) {
        acc[q] += __shfl_xor(acc[q], 16);
        acc[q] += __shfl_xor(acc[q], 32);
    }
    if (eg == 0) {
        unsigned int us[4] = {su.x, su.y, su.z, su.w};
        float4 b0 = ((const float4*)b)[fl * 2];
        float4 b1 = ((const float4*)b)[fl * 2 + 1];
        float bb[8] = {b0.x, b0.y, b0.z, b0.w, b1.x, b1.y, b1.z, b1.w};
        float r[8];
#pragma unroll
        for (int q = 0; q < 4; q++) {
            r[2 * q]     = fmaxf(fmaf(__uint_as_float(us[q] << 16), sl, acc[2 * q]) + bb[2 * q], 0.f);
            r[2 * q + 1] = fmaxf(fmaf(__uint_as_float(us[q] & 0xffff0000u), sl, acc[2 * q + 1]) + bb[2 * q + 1], 0.f);
        }
        uint4 o;
        o.x = (unsigned)f2bf(r[0]) | ((unsigned)f2bf(r[1]) << 16);
        o.y = (unsigned)f2bf(r[2]) | ((unsigned)f2bf(r[3]) << 16);
        o.z = (unsigned)f2bf(r[4]) | ((unsigned)f2bf(r[5]) << 16);
        o.w = (unsigned)f2bf(r[6]) | ((unsigned)f2bf(r[7]) << 16);
        ((uint4*)(H + (size_t)n * 128))[fl] = o;
    }
}

// ---- fused pooling + head: one 512-thread block per graph, no atomics ----
__global__ __launch_bounds__(512) void k_poolhead(const unsigned short* __restrict__ H,
                                                  const int* __restrict__ gstart,
                                                  const float* __restrict__ linW,
                                                  const float* __restrict__ linb,
                                                  float* __restrict__ out) {
    __shared__ float lmx[1024], lsm[1024];
    __shared__ float mxf[128], mnf[128];
    const int g = blockIdx.x, t = threadIdx.x;
    const int slice = t >> 6;        // 0..7 node slices
    const int fp = t & 63;           // feature pair
    const int n0 = gstart[g], n1 = gstart[g + 1];
    float mx0 = 0.f, mx1 = 0.f, sm0 = 0.f, sm1 = 0.f;   // h >= 0 post-relu
    for (int n = n0 + slice; n < n1; n += 8) {
        unsigned int u = *(const unsigned int*)(H + (size_t)n * 128 + fp * 2);
        float v0 = bf2f((unsigned short)(u & 0xffffu));
        float v1 = bf2f((unsigned short)(u >> 16));
        mx0 = fmaxf(mx0, v0); mx1 = fmaxf(mx1, v1);
        sm0 += v0; sm1 += v1;
    }
    lmx[slice * 128 + fp * 2] = mx0; lmx[slice * 128 + fp * 2 + 1] = mx1;
    lsm[slice * 128 + fp * 2] = sm0; lsm[slice * 128 + fp * 2 + 1] = sm1;
    __syncthreads();
    if (t < 128) {
        float m = 0.f, s = 0.f;
#pragma unroll
        for (int q = 0; q < 8; q++) {
            m = fmaxf(m, lmx[q * 128 + t]);
            s += lsm[q * 128 + t];
        }
        mxf[t] = m;
        mnf[t] = s / fmaxf((float)(n1 - n0), 1.0f);
    }
    __syncthreads();
    if (t < CC) {
        float z = linb[t];
        for (int f = 0; f < 128; f++) {
            z = fmaf(mxf[f], linW[f * CC + t], z);
            z = fmaf(mnf[f], linW[(128 + f) * CC + t], z);
        }
        float m = z;
        for (int o = 8; o >= 1; o >>= 1) m = fmaxf(m, __shfl_xor(m, o, 16));
        float ex = expf(z - m), s = ex;
        for (int o = 8; o >= 1; o >>= 1) s += __shfl_xor(s, o, 16);
        out[g * CC + t] = z - m - logf(s);
    }
}

extern "C" void kernel_launch(void* const* d_in, const int* in_sizes, int n_in,
                              void* d_out, int out_size, void* d_ws, size_t ws_size,
                              hipStream_t stream) {
    const float* x    = (const float*)d_in[0];
    const int*   ei   = (const int*)d_in[1];
    const float* ew   = (const float*)d_in[2];
    const int*   batch= (const int*)d_in[3];
    const float* W1   = (const float*)d_in[4];
    const float* b1   = (const float*)d_in[5];
    const float* W2   = (const float*)d_in[6];
    const float* b2   = (const float*)d_in[7];
    const float* linW = (const float*)d_in[8];
    const float* linb = (const float*)d_in[9];
    float* out = (float*)d_out;

    // workspace layout: 16B-aligned buffers first (gload_lds needs aligned src)
    unsigned short* YB = (unsigned short*)d_ws;              // [N,128] bf16 gemm out
    unsigned short* HB = YB + (size_t)NN * 128;              // [N,128] bf16 gather out
    unsigned short* XB = HB + (size_t)NN * 128;              // [N,128] bf16 input
    unsigned short* WT1 = XB + (size_t)NN * 128;             // [128*128]
    unsigned short* WT2 = WT1 + 128 * 128;                   // [128*128]
    int2*  BUCKET = (int2*)(WT2 + 128 * 128);                // [E]
    unsigned long long* DEGC = (unsigned long long*)(BUCKET + EE);  // [N] packed
    float* DINV   = (float*)(DEGC + NN);                     // [N]
    int*   ROWPTR = (int*)(DINV + NN);                       // [N+1]
    int*   RANKE  = ROWPTR + NN + 1;                         // [E]
    int*   GSTART = RANKE + EE;                              // [G+1]
    int*   BS     = GSTART + GG + 1;                         // [NBLK]

    const int* src = ei;
    const int* dst = ei + EE;

    // prep: zero DEGC | W transpose | gstart | x->bf16
    k_prep<<<NBLK + 129 + CONVB, 256, 0, stream>>>(x, XB, W1, W2, WT1, WT2, DEGC, batch, GSTART);

    // layer-1 GEMM (async-staged) with deg tail-fused into every block
    k_gemm_deg<1><<<GEMMB, 256, 0, stream>>>(XB, WT1, YB, NN, dst, ew, DEGC, RANKE);

    // CSR build
    k_scanA<<<NBLK, 256, 0, stream>>>(DEGC, BS, DINV);
    k_scanBC<<<NBLK, 256, 0, stream>>>(BS, DEGC, ROWPTR);
    k_binfill<<<(EE + 255) / 256, 256, 0, stream>>>(src, dst, ew, DINV, ROWPTR, RANKE, BUCKET);

    // layer 1 aggregate
    k_gather<<<(NN + 3) / 4, 256, 0, stream>>>(YB, ROWPTR, BUCKET, DINV, b1, HB);

    // layer 2
    k_gemm_deg<0><<<GEMMB, 256, 0, stream>>>(HB, WT2, YB, NN, nullptr, nullptr, nullptr, nullptr);
    k_gather<<<(NN + 3) / 4, 256, 0, stream>>>(YB, ROWPTR, BUCKET, DINV, b2, HB);

    // pooling + head (one block per graph)
    k_poolhead<<<GG, 512, 0, stream>>>(HB, GSTART, linW, linb, out);
}

// Round 12
// 148.392 us; speedup vs baseline: 1.1873x; 1.0571x over previous
//
#include <hip/hip_runtime.h>
#include <hip/hip_bf16.h>

#define NN 50000
#define EE 600000
#define FH 128
#define GG 128
#define CC 16
#define NBLK ((NN + 255) / 256)   // 196 node blocks
#define GEMMB 782                 // 64-row gemm tiles
#define PP 192                    // edge chunks (hist/fill blocks)
#define EPP 3125                  // edges per chunk (192*3125 == 600000)
#define CONVB 3125                // x->bf16 conversion blocks

typedef __attribute__((ext_vector_type(8))) short bf16x8;
typedef __attribute__((ext_vector_type(4))) float f32x4;

static __device__ __forceinline__ unsigned short f2bf(float f) {
    union { float f; unsigned int u; } v; v.f = f;
    unsigned int r = v.u + 0x7fffu + ((v.u >> 16) & 1u);   // RNE
    return (unsigned short)(r >> 16);
}
static __device__ __forceinline__ float bf2f(unsigned short h) {
    union { unsigned int u; float f; } v; v.u = ((unsigned int)h) << 16;
    return v.f;
}
// async global->LDS, 16B per lane; lds base must be wave-uniform
static __device__ __forceinline__ void ld16(const void* g, void* l) {
    __builtin_amdgcn_global_load_lds((const __attribute__((address_space(1))) void*)g,
                                     (__attribute__((address_space(3))) void*)l, 16, 0, 0);
}

// ---- prep: transpose W1,W2 to bf16 | gstart binary search | x->bf16 ----
__global__ __launch_bounds__(256) void k_prep(const float* __restrict__ x,
                                              unsigned short* __restrict__ XB,
                                              const float* __restrict__ W1,
                                              const float* __restrict__ W2,
                                              unsigned short* __restrict__ WT1,
                                              unsigned short* __restrict__ WT2,
                                              const int* __restrict__ batch,
                                              int* __restrict__ gstart) {
    const int b = blockIdx.x, t = threadIdx.x;
    if (b < 128) {
        int o = b * 256 + t;                   // 0..32767
        const float* W = (o < 16384) ? W1 : W2;
        unsigned short* WT = (o < 16384) ? WT1 : WT2;
        int oo = o & 16383;
        int c = oo >> 7, k = oo & 127;
        WT[oo] = f2bf(W[k * 128 + c]);
    } else if (b == 128) {
        if (t <= GG) {
            int lo = 0, hi = NN;
            while (lo < hi) {
                int mid = (lo + hi) >> 1;
                if (batch[mid] < t) lo = mid + 1; else hi = mid;
            }
            gstart[t] = lo;
        }
    } else {
        int o = (b - 129) * 256 + t;           // 0..799999, 8 floats each
        const float4* xp = (const float4*)x + (size_t)o * 2;
        float4 f0 = xp[0], f1 = xp[1];
        uint4 v;
        v.x = (unsigned)f2bf(f0.x) | ((unsigned)f2bf(f0.y) << 16);
        v.y = (unsigned)f2bf(f0.z) | ((unsigned)f2bf(f0.w) << 16);
        v.z = (unsigned)f2bf(f1.x) | ((unsigned)f2bf(f1.y) << 16);
        v.w = (unsigned)f2bf(f1.z) | ((unsigned)f2bf(f1.w) << 16);
        ((uint4*)XB)[o] = v;
    }
}

// ---- hist: per-chunk LDS u8x4-packed dst histogram -> HIST8[p][50000] ----
__global__ __launch_bounds__(512) void k_hist(const int* __restrict__ dst,
                                              unsigned int* __restrict__ histw) {
    __shared__ unsigned int lh[12500];         // 50000 u8 counts packed x4
    const int b = blockIdx.x, t = threadIdx.x;
    for (int w = t; w < 12500; w += 512) lh[w] = 0u;
    __syncthreads();
    const int e1 = (b + 1) * EPP;
    for (int e = b * EPP + t; e < e1; e += 512) {
        int d = dst[e];
        atomicAdd(&lh[d >> 2], 1u << (8 * (d & 3)));
    }
    __syncthreads();
    for (int w = t; w < 12500; w += 512) histw[(size_t)b * 12500 + w] = lh[w];
}

// ---- scanA: per-node total count + per-chunk cursor bases CB16 + block sums ----
__global__ __launch_bounds__(256) void k_scanA(const unsigned char* __restrict__ hist8,
                                               unsigned short* __restrict__ cb16,
                                               int* __restrict__ cnt,
                                               int* __restrict__ bs) {
    int i = blockIdx.x * 256 + threadIdx.x;
    int run = 0;
    if (i < NN) {
        for (int p = 0; p < PP; p += 32) {
            unsigned char hh[32];
#pragma unroll
            for (int q = 0; q < 32; q++) hh[q] = hist8[(size_t)(p + q) * 50000 + i];
#pragma unroll
            for (int q = 0; q < 32; q++) {
                cb16[(size_t)(p + q) * 50000 + i] = (unsigned short)run;
                run += hh[q];
            }
        }
        cnt[i] = run;
    }
    int v = run;
#pragma unroll
    for (int o = 32; o >= 1; o >>= 1) v += __shfl_down(v, o, 64);
    __shared__ int ws[4];
    if ((threadIdx.x & 63) == 0) ws[threadIdx.x >> 6] = v;
    __syncthreads();
    if (threadIdx.x == 0) bs[blockIdx.x] = ws[0] + ws[1] + ws[2] + ws[3];
}

// ---- scanBC: redundant block-sum scan in LDS + per-chunk scan -> rowptr ----
__global__ __launch_bounds__(256) void k_scanBC(const int* __restrict__ bs,
                                                const int* __restrict__ cnt,
                                                int* __restrict__ rowptr) {
    __shared__ int sb[256];
    __shared__ int sc[256];
    const int t = threadIdx.x, b = blockIdx.x;
    int vb = (t < NBLK) ? bs[t] : 0;
    sb[t] = vb;
    __syncthreads();
    for (int off = 1; off < 256; off <<= 1) {
        int add = (t >= off) ? sb[t - off] : 0;
        __syncthreads();
        sb[t] += add;
        __syncthreads();
    }
    const int boff = (b > 0) ? sb[b - 1] : 0;
    const int i = b * 256 + t;
    int v = (i < NN) ? cnt[i] : 0;
    sc[t] = v;
    __syncthreads();
    for (int off = 1; off < 256; off <<= 1) {
        int add = (t >= off) ? sc[t - off] : 0;
        __syncthreads();
        sc[t] += add;
        __syncthreads();
    }
    int excl = sc[t] - v + boff;
    if (i < NN) rowptr[i] = excl;
    if (i == 0) rowptr[NN] = EE;
}

// ---- fill: replay chunk with LDS returning atomics -> bucket (src, ew) ----
// pos = rowptr[d] + CB16[p][d] + local_rank. No global atomics, no dinv needed.
__global__ __launch_bounds__(512) void k_fill(const int* __restrict__ src,
                                              const int* __restrict__ dst,
                                              const float* __restrict__ ew,
                                              const int* __restrict__ rowptr,
                                              const unsigned short* __restrict__ cb16,
                                              int2* __restrict__ bucket) {
    __shared__ unsigned int lh[12500];
    const int b = blockIdx.x, t = threadIdx.x;
    for (int w = t; w < 12500; w += 512) lh[w] = 0u;
    __syncthreads();
    const int e1 = (b + 1) * EPP;
    for (int e = b * EPP + t; e < e1; e += 512) {
        int d = dst[e];
        int sh = 8 * (d & 3);
        unsigned int old = atomicAdd(&lh[d >> 2], 1u << sh);
        int lr = (int)((old >> sh) & 0xffu);
        int pos = rowptr[d] + (int)cb16[(size_t)b * 50000 + d] + lr;
        bucket[pos] = make_int2(src[e], __float_as_int(ew[e]));
    }
}

// ---- degsum: segmented sum of ew over each node's CSR segment -> dinv ----
__global__ __launch_bounds__(256) void k_degsum(const int* __restrict__ rowptr,
                                                const int2* __restrict__ bucket,
                                                float* __restrict__ dinv) {
    int n = blockIdx.x * 256 + threadIdx.x;
    if (n < NN) {
        float s = 0.f;
        const int e1 = rowptr[n + 1];
        for (int e = rowptr[n]; e < e1; e++) s += __int_as_float(bucket[e].y);
        dinv[n] = rsqrtf(s + 1.0f);
    }
}

// ---- MFMA GEMM (bf16 in, bf16 out), async global_load_lds staging ----
// LDS linear; source column pre-swizzled slot^=(row&7) (both-sides rule #21).
__global__ __launch_bounds__(256, 3) void k_gemm(const unsigned short* __restrict__ Xin,
                                                 const unsigned short* __restrict__ Wt,
                                                 unsigned short* __restrict__ Y,
                                                 int nrows) {
    __shared__ char smem[49152];
    const int tid = threadIdx.x;
    const int lane = tid & 63, w = tid >> 6;
    const int r0 = blockIdx.x * 64;
    const char* Wb = (const char*)Wt;
    const char* Xb = (const char*)Xin;

#pragma unroll
    for (int j = 0; j < 12; j++) {
        const int base = (j * 4 + w) * 64;     // chunk index of lane 0 (uniform)
        const int ci = base + lane;            // 0..3071
        char* ldst = smem + (size_t)base * 16;
        if (base < 2048) {
            int row = ci >> 4, slot = ci & 15;
            ld16(Wb + row * 256 + ((slot ^ (row & 7)) * 16), ldst);
        } else {
            int xci = ci - 2048;
            int row = xci >> 4, slot = xci & 15;
            ld16(Xb + (size_t)(r0 + row) * 256 + ((slot ^ (row & 7)) * 16), ldst);
        }
    }
    __syncthreads();

    const int wr = (w >> 1) * 32, wc = (w & 1) * 64;
    const int lr = lane & 15, lg = lane >> 4;
    f32x4 acc[2][4];
#pragma unroll
    for (int a = 0; a < 2; a++)
#pragma unroll
        for (int c = 0; c < 4; c++) acc[a][c] = (f32x4){0.f, 0.f, 0.f, 0.f};

#pragma unroll
    for (int t = 0; t < 4; t++) {
        const int kb = t * 64 + lg * 16;
        bf16x8 af[2], bf[4];
#pragma unroll
        for (int i = 0; i < 2; i++) {
            int ar = wr + i * 16 + lr;
            af[i] = *(const bf16x8*)(smem + 32768 + ar * 256 + (kb ^ ((ar & 7) << 4)));
        }
#pragma unroll
        for (int i = 0; i < 4; i++) {
            int bc = wc + i * 16 + lr;
            bf[i] = *(const bf16x8*)(smem + bc * 256 + (kb ^ ((bc & 7) << 4)));
        }
#pragma unroll
        for (int fr = 0; fr < 2; fr++)
#pragma unroll
            for (int fc = 0; fc < 4; fc++)
                acc[fr][fc] = __builtin_amdgcn_mfma_f32_16x16x32_bf16(af[fr], bf[fc], acc[fr][fc], 0, 0, 0);
    }

    __syncthreads();
#pragma unroll
    for (int fr = 0; fr < 2; fr++)
#pragma unroll
        for (int fc = 0; fc < 4; fc++)
#pragma unroll
            for (int j = 0; j < 4; j++) {
                int row = wr + fr * 16 + lg * 4 + j;
                int col = wc + fc * 16 + lr;
                *(unsigned short*)(smem + row * 272 + col * 2) = f2bf(acc[fr][fc][j]);
            }
    __syncthreads();
#pragma unroll
    for (int j = 0; j < 4; j++) {
        int ci = tid + 256 * j;
        int row = ci >> 4, slot = ci & 15;
        int grow = r0 + row;
        if (grow < nrows)
            ((uint4*)(Y + (size_t)grow * 128))[slot] = *(const uint4*)(smem + row * 272 + slot * 16);
    }
}

// ---- gather-aggregate + self-loop + bias + relu (bf16 in/out) ----
// nm computed on the fly: dinv[s] * ew * dinv[n].
__global__ __launch_bounds__(256) void k_gather(const unsigned short* __restrict__ XW,
                                                const int* __restrict__ rowptr,
                                                const int2* __restrict__ bucket,
                                                const float* __restrict__ dinv,
                                                const float* __restrict__ b,
                                                unsigned short* __restrict__ H) {
    const int wv = threadIdx.x >> 6, lane = threadIdx.x & 63;
    const int n = blockIdx.x * 4 + wv;
    if (n >= NN) return;
    const int eg = lane >> 4;        // edge group 0..3
    const int fl = lane & 15;        // 16B feature slot
    const float di = dinv[n];
    const float sl = di * di;
    uint4 su = ((const uint4*)(XW + (size_t)n * 128))[fl];
    float acc[8];
#pragma unroll
    for (int q = 0; q < 8; q++) acc[q] = 0.f;
    const int e0 = rowptr[n], e1 = rowptr[n + 1];
    int e = e0 + eg;
    for (; e + 4 < e1; e += 8) {
        int2 p0 = bucket[e];
        int2 p1 = bucket[e + 4];
        float nm0 = dinv[p0.x] * __int_as_float(p0.y) * di;
        float nm1 = dinv[p1.x] * __int_as_float(p1.y) * di;
        uint4 v0 = ((const uint4*)(XW + (size_t)p0.x * 128))[fl];
        uint4 v1 = ((const uint4*)(XW + (size_t)p1.x * 128))[fl];
        unsigned int u0[4] = {v0.x, v0.y, v0.z, v0.w};
        unsigned int u1[4] = {v1.x, v1.y, v1.z, v1.w};
#pragma unroll
        for (int q = 0; q < 4; q++) {
            acc[2 * q]     = fmaf(__uint_as_float(u0[q] << 16), nm0, acc[2 * q]);
            acc[2 * q + 1] = fmaf(__uint_as_float(u0[q] & 0xffff0000u), nm0, acc[2 * q + 1]);
            acc[2 * q]     = fmaf(__uint_as_float(u1[q] << 16), nm1, acc[2 * q]);
            acc[2 * q + 1] = fmaf(__uint_as_float(u1[q] & 0xffff0000u), nm1, acc[2 * q + 1]);
        }
    }
    if (e < e1) {
        int2 p = bucket[e];
        float nm = dinv[p.x] * __int_as_float(p.y) * di;
        uint4 v = ((const uint4*)(XW + (size_t)p.x * 128))[fl];
        unsigned int uu[4] = {v.x, v.y, v.z, v.w};
#pragma unroll
        for (int q = 0; q < 4; q++) {
            acc[2 * q]     = fmaf(__uint_as_float(uu[q] << 16), nm, acc[2 * q]);
            acc[2 * q + 1] = fmaf(__uint_as_float(uu[q] & 0xffff0000u), nm, acc[2 * q + 1]);
        }
    }
#pragma unroll
    for (int q = 0; q < 8; q++) {
        acc[q] += __shfl_xor(acc[q], 16);
        acc[q] += __shfl_xor(acc[q], 32);
    }
    if (eg == 0) {
        unsigned int us[4] = {su.x, su.y, su.z, su.w};
        float4 b0 = ((const float4*)b)[fl * 2];
        float4 b1 = ((const float4*)b)[fl * 2 + 1];
        float bb[8] = {b0.x, b0.y, b0.z, b0.w, b1.x, b1.y, b1.z, b1.w};
        float r[8];
#pragma unroll
        for (int q = 0; q < 4; q++) {
            r[2 * q]     = fmaxf(fmaf(__uint_as_float(us[q] << 16), sl, acc[2 * q]) + bb[2 * q], 0.f);
            r[2 * q + 1] = fmaxf(fmaf(__uint_as_float(us[q] & 0xffff0000u), sl, acc[2 * q + 1]) + bb[2 * q + 1], 0.f);
        }
        uint4 o;
        o.x = (unsigned)f2bf(r[0]) | ((unsigned)f2bf(r[1]) << 16);
        o.y = (unsigned)f2bf(r[2]) | ((unsigned)f2bf(r[3]) << 16);
        o.z = (unsigned)f2bf(r[4]) | ((unsigned)f2bf(r[5]) << 16);
        o.w = (unsigned)f2bf(r[6]) | ((unsigned)f2bf(r[7]) << 16);
        ((uint4*)(H + (size_t)n * 128))[fl] = o;
    }
}

// ---- fused pooling + head: one 512-thread block per graph, no atomics ----
__global__ __launch_bounds__(512) void k_poolhead(const unsigned short* __restrict__ H,
                                                  const int* __restrict__ gstart,
                                                  const float* __restrict__ linW,
                                                  const float* __restrict__ linb,
                                                  float* __restrict__ out) {
    __shared__ float lmx[1024], lsm[1024];
    __shared__ float mxf[128], mnf[128];
    const int g = blockIdx.x, t = threadIdx.x;
    const int slice = t >> 6;        // 0..7 node slices
    const int fp = t & 63;           // feature pair
    const int n0 = gstart[g], n1 = gstart[g + 1];
    float mx0 = 0.f, mx1 = 0.f, sm0 = 0.f, sm1 = 0.f;   // h >= 0 post-relu
    for (int n = n0 + slice; n < n1; n += 8) {
        unsigned int u = *(const unsigned int*)(H + (size_t)n * 128 + fp * 2);
        float v0 = bf2f((unsigned short)(u & 0xffffu));
        float v1 = bf2f((unsigned short)(u >> 16));
        mx0 = fmaxf(mx0, v0); mx1 = fmaxf(mx1, v1);
        sm0 += v0; sm1 += v1;
    }
    lmx[slice * 128 + fp * 2] = mx0; lmx[slice * 128 + fp * 2 + 1] = mx1;
    lsm[slice * 128 + fp * 2] = sm0; lsm[slice * 128 + fp * 2 + 1] = sm1;
    __syncthreads();
    if (t < 128) {
        float m = 0.f, s = 0.f;
#pragma unroll
        for (int q = 0; q < 8; q++) {
            m = fmaxf(m, lmx[q * 128 + t]);
            s += lsm[q * 128 + t];
        }
        mxf[t] = m;
        mnf[t] = s / fmaxf((float)(n1 - n0), 1.0f);
    }
    __syncthreads();
    if (t < CC) {
        float z = linb[t];
        for (int f = 0; f < 128; f++) {
            z = fmaf(mxf[f], linW[f * CC + t], z);
            z = fmaf(mnf[f], linW[(128 + f) * CC + t], z);
        }
        float m = z;
        for (int o = 8; o >= 1; o >>= 1) m = fmaxf(m, __shfl_xor(m, o, 16));
        float ex = expf(z - m), s = ex;
        for (int o = 8; o >= 1; o >>= 1) s += __shfl_xor(s, o, 16);
        out[g * CC + t] = z - m - logf(s);
    }
}

extern "C" void kernel_launch(void* const* d_in, const int* in_sizes, int n_in,
                              void* d_out, int out_size, void* d_ws, size_t ws_size,
                              hipStream_t stream) {
    const float* x    = (const float*)d_in[0];
    const int*   ei   = (const int*)d_in[1];
    const float* ew   = (const float*)d_in[2];
    const int*   batch= (const int*)d_in[3];
    const float* W1   = (const float*)d_in[4];
    const float* b1   = (const float*)d_in[5];
    const float* W2   = (const float*)d_in[6];
    const float* b2   = (const float*)d_in[7];
    const float* linW = (const float*)d_in[8];
    const float* linb = (const float*)d_in[9];
    float* out = (float*)d_out;

    // workspace layout: 16B-aligned buffers first
    unsigned short* YB = (unsigned short*)d_ws;              // [N,128] bf16 gemm out
    unsigned short* HB = YB + (size_t)NN * 128;              // [N,128] bf16 gather out
    unsigned short* XB = HB + (size_t)NN * 128;              // [N,128] bf16 input
    unsigned short* WT1 = XB + (size_t)NN * 128;             // [128*128]
    unsigned short* WT2 = WT1 + 128 * 128;                   // [128*128]
    int2*  BUCKET = (int2*)(WT2 + 128 * 128);                // [E] (src, ew)
    float* DINV   = (float*)(BUCKET + EE);                   // [N]
    int*   ROWPTR = (int*)(DINV + NN);                       // [N+1]
    int*   CNT    = ROWPTR + NN + 1;                         // [N]
    int*   GSTART = CNT + NN;                                // [G+1]
    int*   BS     = GSTART + GG + 1;                         // [NBLK]
    unsigned int* HISTW = (unsigned int*)(BS + NBLK + 1);    // [PP][12500] u8x4
    unsigned short* CB16 = (unsigned short*)(HISTW + (size_t)PP * 12500); // [PP][50000]

    const int* src = ei;
    const int* dst = ei + EE;

    // prep: W transpose | gstart | x->bf16
    k_prep<<<129 + CONVB, 256, 0, stream>>>(x, XB, W1, W2, WT1, WT2, batch, GSTART);

    // layer-1 GEMM (independent of CSR build)
    k_gemm<<<GEMMB, 256, 0, stream>>>(XB, WT1, YB, NN);

    // CSR build — no global atomics anywhere
    k_hist<<<PP, 512, 0, stream>>>(dst, HISTW);
    k_scanA<<<NBLK, 256, 0, stream>>>((const unsigned char*)HISTW, CB16, CNT, BS);
    k_scanBC<<<NBLK, 256, 0, stream>>>(BS, CNT, ROWPTR);
    k_fill<<<PP, 512, 0, stream>>>(src, dst, ew, ROWPTR, CB16, BUCKET);
    k_degsum<<<NBLK, 256, 0, stream>>>(ROWPTR, BUCKET, DINV);

    // layer 1 aggregate
    k_gather<<<(NN + 3) / 4, 256, 0, stream>>>(YB, ROWPTR, BUCKET, DINV, b1, HB);

    // layer 2
    k_gemm<<<GEMMB, 256, 0, stream>>>(HB, WT2, YB, NN);
    k_gather<<<(NN + 3) / 4, 256, 0, stream>>>(YB, ROWPTR, BUCKET, DINV, b2, HB);

    // pooling + head (one block per graph)
    k_poolhead<<<GG, 512, 0, stream>>>(HB, GSTART, linW, linb, out);
}